// Round 8
// baseline (4513.944 us; speedup 1.0000x reference)
//
#include <hip/hip_runtime.h>

// Problem constants (from reference)
#define NNODES 10000
#define NEDGES 320000
#define KDIM   256     // NIN
#define NH     8       // heads
#define CH     32      // channels/head
#define ND     256     // NH*CH

// ---------------- GEMM: out = x @ W + b (fp32, vector ALU) ----------------
#define BM 64
#define BN 64
#define BK 16
#define PAD_A 4   // As row stride 68 floats = 272B, keeps float4 reads 16B-aligned

__global__ __launch_bounds__(256) void proj_gemm_kernel(
    const float* __restrict__ x,
    const float* __restrict__ Wq, const float* __restrict__ bq,
    const float* __restrict__ Wk, const float* __restrict__ bk,
    const float* __restrict__ Wv, const float* __restrict__ bv,
    const float* __restrict__ Wsk, const float* __restrict__ bsk,
    float* __restrict__ q, float* __restrict__ k, float* __restrict__ v,
    float* __restrict__ outp)
{
    __shared__ float As[BK][BM + PAD_A];   // transposed A tile: As[kk][row]
    __shared__ float Bs[BK][BN];

    const int mat = blockIdx.z;
    const float* W; const float* bias; float* dst;
    if (mat == 0)      { W = Wq;  bias = bq;  dst = q;    }
    else if (mat == 1) { W = Wk;  bias = bk;  dst = k;    }
    else if (mat == 2) { W = Wv;  bias = bv;  dst = v;    }
    else               { W = Wsk; bias = bsk; dst = outp; }

    const int tid  = threadIdx.x;
    const int tx   = tid & 15;    // 0..15 -> 4 output cols each
    const int ty   = tid >> 4;    // 0..15 -> 4 output rows each
    const int row0 = blockIdx.x * BM;
    const int col0 = blockIdx.y * BN;

    // A tile load mapping: 256 thr * float4 = 64 rows x 16 k
    const int ar   = tid >> 2;          // 0..63 row within tile
    const int ak   = (tid & 3) * 4;     // 0,4,8,12 k offset
    const int arow = min(row0 + ar, NNODES - 1);  // clamp (stores are guarded)

    // B tile load mapping: 16 rows x 64 cols
    const int brow = tid >> 4;          // 0..15
    const int bcol = (tid & 15) * 4;    // 0..60

    float acc[4][4] = {};

    for (int kt = 0; kt < KDIM; kt += BK) {
        const float4 av  = *(const float4*)(x + (size_t)arow * KDIM + kt + ak);
        const float4 bv4 = *(const float4*)(W + (size_t)(kt + brow) * ND + col0 + bcol);
        As[ak + 0][ar] = av.x;
        As[ak + 1][ar] = av.y;
        As[ak + 2][ar] = av.z;
        As[ak + 3][ar] = av.w;
        *(float4*)&Bs[brow][bcol] = bv4;
        __syncthreads();

        #pragma unroll
        for (int kk = 0; kk < BK; ++kk) {
            const float4 a4 = *(const float4*)&As[kk][ty * 4];
            const float4 b4 = *(const float4*)&Bs[kk][tx * 4];
            const float aa[4] = {a4.x, a4.y, a4.z, a4.w};
            const float bb[4] = {b4.x, b4.y, b4.z, b4.w};
            #pragma unroll
            for (int i = 0; i < 4; ++i)
                #pragma unroll
                for (int j = 0; j < 4; ++j)
                    acc[i][j] += aa[i] * bb[j];
        }
        __syncthreads();
    }

    const float4 bb4 = *(const float4*)(bias + col0 + tx * 4);
    const float badd[4] = {bb4.x, bb4.y, bb4.z, bb4.w};
    #pragma unroll
    for (int i = 0; i < 4; ++i) {
        const int row = row0 + ty * 4 + i;
        if (row < NNODES) {
            float4 o;
            o.x = acc[i][0] + badd[0];
            o.y = acc[i][1] + badd[1];
            o.z = acc[i][2] + badd[2];
            o.w = acc[i][3] + badd[3];
            *(float4*)(dst + (size_t)row * ND + col0 + tx * 4) = o;
        }
    }
}

// ---------------- monotone float<->uint encoding for atomicMax ----------------
__device__ inline unsigned int enc_f32(float f) {
    unsigned int b = __float_as_uint(f);
    return (b & 0x80000000u) ? ~b : (b | 0x80000000u);
}
__device__ inline float dec_f32(unsigned int kx) {
    unsigned int b = (kx & 0x80000000u) ? (kx & 0x7FFFFFFFu) : ~kx;
    return __uint_as_float(b);
}

// ---------------- per-(edge,head) score + scatter max ----------------
__global__ __launch_bounds__(256) void score_kernel(
    const float* __restrict__ q, const float* __restrict__ k,
    const int* __restrict__ srcI, const int* __restrict__ dstI,
    float* __restrict__ score, unsigned int* __restrict__ mkeys)
{
    const int idx = blockIdx.x * 256 + threadIdx.x;
    if (idx >= NEDGES * NH) return;
    const int e = idx >> 3;
    const int h = idx & 7;
    const int s = srcI[e];
    const int d = dstI[e];

    const float4* qp = (const float4*)(q + (size_t)d * ND + h * CH);
    const float4* kp = (const float4*)(k + (size_t)s * ND + h * CH);
    float acc = 0.0f;
    #pragma unroll
    for (int i = 0; i < CH / 4; ++i) {
        const float4 a = qp[i];
        const float4 b = kp[i];
        acc += a.x * b.x + a.y * b.y + a.z * b.z + a.w * b.w;
    }
    acc *= 0.17677669529663687f;   // 1/sqrt(32)
    score[idx] = acc;
    atomicMax(mkeys + (size_t)d * NH + h, enc_f32(acc));
}

// ---------------- exp(score - max) + scatter denom ----------------
__global__ __launch_bounds__(256) void ex_kernel(
    const int* __restrict__ dstI,
    float* __restrict__ score,            // in: score, out: ex
    const unsigned int* __restrict__ mkeys,
    float* __restrict__ denom)
{
    const int idx = blockIdx.x * 256 + threadIdx.x;
    if (idx >= NEDGES * NH) return;
    const int e = idx >> 3;
    const int h = idx & 7;
    const int d = dstI[e];
    const float m = dec_f32(mkeys[(size_t)d * NH + h]);
    const float ex = expf(score[idx] - m);
    score[idx] = ex;
    atomicAdd(denom + (size_t)d * NH + h, ex);
}

// ---------------- alpha * v[src] scatter-add into out ----------------
__global__ __launch_bounds__(256) void scatter_kernel(
    const float* __restrict__ v,
    const int* __restrict__ srcI, const int* __restrict__ dstI,
    const float* __restrict__ ex, const float* __restrict__ denom,
    float* __restrict__ outp)
{
    const int idx = blockIdx.x * 256 + threadIdx.x;
    if (idx >= NEDGES * NH) return;
    const int e = idx >> 3;
    const int h = idx & 7;
    const int s = srcI[e];
    const int d = dstI[e];
    const float alpha = ex[idx] / denom[(size_t)d * NH + h];

    const float4* vp = (const float4*)(v + (size_t)s * ND + h * CH);
    float* op = outp + (size_t)d * ND + h * CH;
    #pragma unroll
    for (int i = 0; i < CH / 4; ++i) {
        const float4 vv = vp[i];
        atomicAdd(op + 4 * i + 0, alpha * vv.x);
        atomicAdd(op + 4 * i + 1, alpha * vv.y);
        atomicAdd(op + 4 * i + 2, alpha * vv.z);
        atomicAdd(op + 4 * i + 3, alpha * vv.w);
    }
}

extern "C" void kernel_launch(void* const* d_in, const int* in_sizes, int n_in,
                              void* d_out, int out_size, void* d_ws, size_t ws_size,
                              hipStream_t stream)
{
    const float* x   = (const float*)d_in[0];
    const int*   ei  = (const int*)d_in[1];   // [2, E] int32 per harness contract
    const float* Wq  = (const float*)d_in[2];
    const float* bq  = (const float*)d_in[3];
    const float* Wk  = (const float*)d_in[4];
    const float* bk  = (const float*)d_in[5];
    const float* Wv  = (const float*)d_in[6];
    const float* bv  = (const float*)d_in[7];
    const float* Wsk = (const float*)d_in[8];
    const float* bsk = (const float*)d_in[9];
    float* outp = (float*)d_out;

    // workspace layout (fp32): q, k, v [N*ND each], score/ex [E*NH], mkeys, denom
    float* q   = (float*)d_ws;
    float* k   = q + (size_t)NNODES * ND;
    float* v   = k + (size_t)NNODES * ND;
    float* sc  = v + (size_t)NNODES * ND;
    unsigned int* mk = (unsigned int*)(sc + (size_t)NEDGES * NH);
    // denom sits right after mkeys; zero both with one memset
    float* den = (float*)(mk + (size_t)NNODES * NH);
    (void)hipMemsetAsync(mk, 0, (size_t)NNODES * NH * sizeof(unsigned int) * 2, stream);

    const int* srcI = ei;            // edge_index[0] = source j
    const int* dstI = ei + NEDGES;   // edge_index[1] = target i

    dim3 gGemm((NNODES + BM - 1) / BM, ND / BN, 4);
    proj_gemm_kernel<<<gGemm, 256, 0, stream>>>(x, Wq, bq, Wk, bk, Wv, bv, Wsk, bsk,
                                                q, k, v, outp);

    const int nEH = NEDGES * NH;
    const int eb  = (nEH + 255) / 256;
    score_kernel<<<eb, 256, 0, stream>>>(q, k, srcI, dstI, sc, mk);
    ex_kernel<<<eb, 256, 0, stream>>>(dstI, sc, mk, den);
    scatter_kernel<<<eb, 256, 0, stream>>>(v, srcI, dstI, sc, den, outp);
}

// Round 9
// 459.074 us; speedup vs baseline: 9.8327x; 9.8327x over previous
//
#include <hip/hip_runtime.h>

// Problem constants (from reference)
#define NNODES 10000
#define NEDGES 320000
#define KDIM   256     // NIN
#define NH     8       // heads
#define CH     32      // channels/head
#define ND     256     // NH*CH

// ---------------- GEMM: out = x @ W + b (fp32, vector ALU) ----------------
#define BM 64
#define BN 64
#define BK 16
#define PAD_A 4

__global__ __launch_bounds__(256) void proj_gemm_kernel(
    const float* __restrict__ x,
    const float* __restrict__ Wq, const float* __restrict__ bq,
    const float* __restrict__ Wk, const float* __restrict__ bk,
    const float* __restrict__ Wv, const float* __restrict__ bv,
    const float* __restrict__ Wsk, const float* __restrict__ bsk,
    float* __restrict__ q, float* __restrict__ k, float* __restrict__ v,
    float* __restrict__ outp)
{
    __shared__ float As[BK][BM + PAD_A];
    __shared__ float Bs[BK][BN];

    const int mat = blockIdx.z;
    const float* W; const float* bias; float* dst;
    if (mat == 0)      { W = Wq;  bias = bq;  dst = q;    }
    else if (mat == 1) { W = Wk;  bias = bk;  dst = k;    }
    else if (mat == 2) { W = Wv;  bias = bv;  dst = v;    }
    else               { W = Wsk; bias = bsk; dst = outp; }

    const int tid  = threadIdx.x;
    const int tx   = tid & 15;
    const int ty   = tid >> 4;
    const int row0 = blockIdx.x * BM;
    const int col0 = blockIdx.y * BN;

    const int ar   = tid >> 2;
    const int ak   = (tid & 3) * 4;
    const int arow = min(row0 + ar, NNODES - 1);

    const int brow = tid >> 4;
    const int bcol = (tid & 15) * 4;

    float acc[4][4] = {};

    for (int kt = 0; kt < KDIM; kt += BK) {
        const float4 av  = *(const float4*)(x + (size_t)arow * KDIM + kt + ak);
        const float4 bv4 = *(const float4*)(W + (size_t)(kt + brow) * ND + col0 + bcol);
        As[ak + 0][ar] = av.x;
        As[ak + 1][ar] = av.y;
        As[ak + 2][ar] = av.z;
        As[ak + 3][ar] = av.w;
        *(float4*)&Bs[brow][bcol] = bv4;
        __syncthreads();

        #pragma unroll
        for (int kk = 0; kk < BK; ++kk) {
            const float4 a4 = *(const float4*)&As[kk][ty * 4];
            const float4 b4 = *(const float4*)&Bs[kk][tx * 4];
            const float aa[4] = {a4.x, a4.y, a4.z, a4.w};
            const float bb[4] = {b4.x, b4.y, b4.z, b4.w};
            #pragma unroll
            for (int i = 0; i < 4; ++i)
                #pragma unroll
                for (int j = 0; j < 4; ++j)
                    acc[i][j] += aa[i] * bb[j];
        }
        __syncthreads();
    }

    const float4 bb4 = *(const float4*)(bias + col0 + tx * 4);
    const float badd[4] = {bb4.x, bb4.y, bb4.z, bb4.w};
    #pragma unroll
    for (int i = 0; i < 4; ++i) {
        const int row = row0 + ty * 4 + i;
        if (row < NNODES) {
            float4 o;
            o.x = acc[i][0] + badd[0];
            o.y = acc[i][1] + badd[1];
            o.z = acc[i][2] + badd[2];
            o.w = acc[i][3] + badd[3];
            *(float4*)(dst + (size_t)row * ND + col0 + tx * 4) = o;
        }
    }
}

// ---------------- CSR build: histogram of dst ----------------
__global__ __launch_bounds__(256) void hist_kernel(
    const int* __restrict__ dstI, int* __restrict__ deg)
{
    const int e = blockIdx.x * 256 + threadIdx.x;
    if (e < NEDGES) atomicAdd(&deg[dstI[e]], 1);
}

// ---------------- CSR build: exclusive prefix scan (single block) ----------------
#define SCAN_PER_T 40   // 256 * 40 = 10240 >= NNODES
__global__ __launch_bounds__(256) void scan_kernel(
    const int* __restrict__ deg, int* __restrict__ rowptr)
{
    __shared__ int part[256];
    const int t = threadIdx.x;
    const int base = t * SCAN_PER_T;

    int s = 0;
    for (int i = 0; i < SCAN_PER_T; ++i) {
        const int idx = base + i;
        if (idx < NNODES) s += deg[idx];
    }
    part[t] = s;
    __syncthreads();

    // Hillis-Steele inclusive scan over 256 partials
    for (int off = 1; off < 256; off <<= 1) {
        int val = 0;
        if (t >= off) val = part[t - off];
        __syncthreads();
        if (t >= off) part[t] += val;
        __syncthreads();
    }

    int run = (t == 0) ? 0 : part[t - 1];
    for (int i = 0; i < SCAN_PER_T; ++i) {
        const int idx = base + i;
        if (idx < NNODES) {
            rowptr[idx] = run;
            run += deg[idx];
        } else if (idx == NNODES) {
            rowptr[NNODES] = run;   // == NEDGES
        }
    }
}

// ---------------- CSR build: fill buckets (order within bucket irrelevant) ----
__global__ __launch_bounds__(256) void fill_kernel(
    const int* __restrict__ dstI, int* __restrict__ deg,   // deg consumed as cursor
    const int* __restrict__ rowptr, int* __restrict__ ebuf)
{
    const int e = blockIdx.x * 256 + threadIdx.x;
    if (e >= NEDGES) return;
    const int d = dstI[e];
    const int p = atomicSub(&deg[d], 1) - 1;   // position in [0, deg)
    ebuf[rowptr[d] + p] = e;
}

// ---------------- per-(edge,head) attention logits (no atomics) ----------------
__global__ __launch_bounds__(256) void score_kernel(
    const float* __restrict__ q, const float* __restrict__ k,
    const int* __restrict__ srcI, const int* __restrict__ dstI,
    float* __restrict__ sc)
{
    const int idx = blockIdx.x * 256 + threadIdx.x;
    if (idx >= NEDGES * NH) return;
    const int e = idx >> 3;
    const int h = idx & 7;
    const int s = srcI[e];
    const int d = dstI[e];

    const float4* qp = (const float4*)(q + (size_t)d * ND + h * CH);
    const float4* kp = (const float4*)(k + (size_t)s * ND + h * CH);
    float acc = 0.0f;
    #pragma unroll
    for (int i = 0; i < CH / 4; ++i) {
        const float4 a = qp[i];
        const float4 b = kp[i];
        acc += a.x * b.x + a.y * b.y + a.z * b.z + a.w * b.w;
    }
    sc[idx] = acc * 0.17677669529663687f;   // 1/sqrt(32)
}

// ---------------- per-node gather: softmax + weighted V, no atomics ----------
// One block per dst node; thread t = (h = t>>5, c = t&31) owns out[d][t].
// out = skip (already stored) + (sum_j p_j * v[src_j]) / (sum_j p_j),
// p_j = exp(sc_j - max_j sc_j).
__global__ __launch_bounds__(256) void gather_kernel(
    const float* __restrict__ v, const float* __restrict__ sc,
    const int* __restrict__ srcI,
    const int* __restrict__ rowptr, const int* __restrict__ ebuf,
    float* __restrict__ outp)
{
    const int d   = blockIdx.x;
    const int t   = threadIdx.x;
    const int h   = t >> 5;
    const int beg = rowptr[d];
    const int end = rowptr[d + 1];
    if (beg == end) return;   // no incoming edges: out = skip only

    float m = -3.0e38f;
    for (int j = beg; j < end; ++j) {
        const int e = ebuf[j];
        m = fmaxf(m, sc[(size_t)e * NH + h]);
    }

    float den = 0.0f, acc = 0.0f;
    for (int j = beg; j < end; ++j) {
        const int e = ebuf[j];
        const int s = srcI[e];
        const float p = __expf(sc[(size_t)e * NH + h] - m);
        den += p;
        acc += p * v[(size_t)s * ND + t];
    }

    outp[(size_t)d * ND + t] += acc / den;
}

extern "C" void kernel_launch(void* const* d_in, const int* in_sizes, int n_in,
                              void* d_out, int out_size, void* d_ws, size_t ws_size,
                              hipStream_t stream)
{
    const float* x   = (const float*)d_in[0];
    const int*   ei  = (const int*)d_in[1];   // [2, E] int32 per harness contract
    const float* Wq  = (const float*)d_in[2];
    const float* bq  = (const float*)d_in[3];
    const float* Wk  = (const float*)d_in[4];
    const float* bk  = (const float*)d_in[5];
    const float* Wv  = (const float*)d_in[6];
    const float* bv  = (const float*)d_in[7];
    const float* Wsk = (const float*)d_in[8];
    const float* bsk = (const float*)d_in[9];
    float* outp = (float*)d_out;

    // workspace layout: q,k,v,sc fp32 [2.56M each]; then CSR ints
    float* q   = (float*)d_ws;
    float* k   = q + (size_t)NNODES * ND;
    float* v   = k + (size_t)NNODES * ND;
    float* sc  = v + (size_t)NNODES * ND;
    int* deg    = (int*)(sc + (size_t)NEDGES * NH);
    int* rowptr = deg + NNODES;          // NNODES+1 entries
    int* ebuf   = rowptr + (NNODES + 1); // NEDGES entries
    // total ~42.3 MB

    const int* srcI = ei;            // edge_index[0] = source j
    const int* dstI = ei + NEDGES;   // edge_index[1] = target i (softmax index)

    // zero only deg; everything else is fully overwritten each launch
    (void)hipMemsetAsync(deg, 0, NNODES * sizeof(int), stream);

    const int eb = (NEDGES + 255) / 256;
    hist_kernel<<<eb, 256, 0, stream>>>(dstI, deg);
    scan_kernel<<<1, 256, 0, stream>>>(deg, rowptr);
    fill_kernel<<<eb, 256, 0, stream>>>(dstI, deg, rowptr, ebuf);

    dim3 gGemm((NNODES + BM - 1) / BM, ND / BN, 4);
    proj_gemm_kernel<<<gGemm, 256, 0, stream>>>(x, Wq, bq, Wk, bk, Wv, bv, Wsk, bsk,
                                                q, k, v, outp);

    const int sb = (NEDGES * NH + 255) / 256;
    score_kernel<<<sb, 256, 0, stream>>>(q, k, srcI, dstI, sc);

    gather_kernel<<<NNODES, 256, 0, stream>>>(v, sc, srcI, rowptr, ebuf, outp);
}

// Round 12
// 419.200 us; speedup vs baseline: 10.7680x; 1.0951x over previous
//
#include <hip/hip_runtime.h>

#define NNODES 10000
#define NEDGES 320000
#define KDIM   256     // NIN
#define NH     8       // heads
#define CH     32      // channels/head
#define ND     256     // NH*CH

typedef unsigned short u16;
typedef __attribute__((ext_vector_type(8))) short bf16x8;   // 8 bf16 (4 VGPRs)
typedef __attribute__((ext_vector_type(8))) u16  u16x8;
typedef __attribute__((ext_vector_type(4))) float f32x4;

__device__ inline u16 f2bf(float f) {   // round-to-nearest-even f32 -> bf16
    unsigned int u = __float_as_uint(f);
    return (u16)((u + 0x7FFFu + ((u >> 16) & 1u)) >> 16);
}

// ---------------- convert x -> bf16 (vectorized, 8 elems/thread) ----------------
__global__ __launch_bounds__(256) void convx_kernel(
    const float* __restrict__ x, u16* __restrict__ xb)
{
    const size_t i8 = (size_t)(blockIdx.x * 256 + threadIdx.x) * 8;
    const float4 a = *(const float4*)(x + i8);
    const float4 b = *(const float4*)(x + i8 + 4);
    u16x8 o;
    o[0] = f2bf(a.x); o[1] = f2bf(a.y); o[2] = f2bf(a.z); o[3] = f2bf(a.w);
    o[4] = f2bf(b.x); o[5] = f2bf(b.y); o[6] = f2bf(b.z); o[7] = f2bf(b.w);
    *(u16x8*)(xb + i8) = o;
}

// ---------------- convert+transpose W -> wt[mat][n][k] bf16 ----------------
__global__ __launch_bounds__(256) void convw_kernel(
    const float* __restrict__ Wq, const float* __restrict__ Wk,
    const float* __restrict__ Wv, const float* __restrict__ Wsk,
    u16* __restrict__ wt)
{
    const int tid = blockIdx.x * 256 + threadIdx.x;   // 0..262143
    const int mat = tid >> 16;
    const int rem = tid & 65535;
    const int n   = rem >> 8;
    const int kk  = rem & 255;
    const float* W = (mat == 0) ? Wq : (mat == 1) ? Wk : (mat == 2) ? Wv : Wsk;
    wt[tid] = f2bf(W[kk * 256 + n]);   // wt[mat][n][kk] = W[kk][n]
}

// ---------------- MFMA GEMM: dst = xb @ W + b (bf16 in, f32 out) ----------------
#define GBM 128
#define GBK 32
#define LDA 40   // padded LDS row stride (bf16 units): 80B breaks stride-64B conflicts

__global__ __launch_bounds__(256) void mfma_gemm_kernel(
    const u16* __restrict__ xb, const u16* __restrict__ wt,
    const float* __restrict__ bq, const float* __restrict__ bk,
    const float* __restrict__ bv, const float* __restrict__ bsk,
    float* __restrict__ q, float* __restrict__ k, float* __restrict__ v,
    float* __restrict__ outp)
{
    __shared__ u16 As[GBM * LDA];
    __shared__ u16 Bs[GBM * LDA];

    const int mat = blockIdx.z;
    const float* bias; float* dst;
    if (mat == 0)      { bias = bq;  dst = q;    }
    else if (mat == 1) { bias = bk;  dst = k;    }
    else if (mat == 2) { bias = bv;  dst = v;    }
    else               { bias = bsk; dst = outp; }

    const int tid  = threadIdx.x;
    const int lane = tid & 63;
    const int wid  = tid >> 6;      // 4 waves
    const int wr   = wid >> 1;      // wave row quadrant (0..1)
    const int wc   = wid & 1;       // wave col quadrant (0..1)
    const int row0 = blockIdx.x * GBM;
    const int col0 = blockIdx.y * GBM;   // N=256 -> blockIdx.y in {0,1}

    const int fr = lane & 15;           // row (A) / col (B) within 16x16 frag
    const int kg = (lane >> 4) * 8;     // k-group offset within 32

    f32x4 acc[4][4] = {};

    const u16* wbase = wt + (size_t)mat * 65536;

    for (int kt = 0; kt < KDIM; kt += GBK) {
        #pragma unroll
        for (int it = 0; it < 2; ++it) {
            const int c   = tid + it * 256;   // chunk 0..511
            const int row = c >> 2;           // 0..127
            const int k8  = (c & 3) * 8;      // 0,8,16,24
            const int ga  = min(row0 + row, NNODES - 1);
            *(bf16x8*)&As[row * LDA + k8] =
                *(const bf16x8*)(xb + (size_t)ga * KDIM + kt + k8);
            *(bf16x8*)&Bs[row * LDA + k8] =
                *(const bf16x8*)(wbase + (size_t)(col0 + row) * KDIM + kt + k8);
        }
        __syncthreads();

        bf16x8 a[4], b[4];
        #pragma unroll
        for (int i = 0; i < 4; ++i)
            a[i] = *(bf16x8*)&As[(wr * 64 + i * 16 + fr) * LDA + kg];
        #pragma unroll
        for (int j = 0; j < 4; ++j)
            b[j] = *(bf16x8*)&Bs[(wc * 64 + j * 16 + fr) * LDA + kg];

        #pragma unroll
        for (int i = 0; i < 4; ++i)
            #pragma unroll
            for (int j = 0; j < 4; ++j)
                acc[i][j] = __builtin_amdgcn_mfma_f32_16x16x32_bf16(
                    a[i], b[j], acc[i][j], 0, 0, 0);
        __syncthreads();
    }

    // epilogue: C/D layout col=lane&15, row=(lane>>4)*4+reg  [m89-verified]
    #pragma unroll
    for (int j = 0; j < 4; ++j) {
        const int ccol = col0 + wc * 64 + j * 16 + (lane & 15);
        const float bb = bias[ccol];
        #pragma unroll
        for (int i = 0; i < 4; ++i) {
            const int rbase = row0 + wr * 64 + i * 16 + (lane >> 4) * 4;
            #pragma unroll
            for (int r = 0; r < 4; ++r) {
                const int row = rbase + r;
                if (row < NNODES)
                    dst[(size_t)row * ND + ccol] = acc[i][j][r] + bb;
            }
        }
    }
}

// ---------------- CSR build: histogram of dst ----------------
__global__ __launch_bounds__(256) void hist_kernel(
    const int* __restrict__ dstI, int* __restrict__ deg)
{
    const int e = blockIdx.x * 256 + threadIdx.x;
    if (e < NEDGES) atomicAdd(&deg[dstI[e]], 1);
}

// ---------------- CSR build: exclusive prefix scan (single block) ----------------
#define SCAN_PER_T 40   // 256 * 40 = 10240 >= NNODES
__global__ __launch_bounds__(256) void scan_kernel(
    const int* __restrict__ deg, int* __restrict__ rowptr)
{
    __shared__ int part[256];
    const int t = threadIdx.x;
    const int base = t * SCAN_PER_T;

    int s = 0;
    for (int i = 0; i < SCAN_PER_T; ++i) {
        const int idx = base + i;
        if (idx < NNODES) s += deg[idx];
    }
    part[t] = s;
    __syncthreads();

    for (int off = 1; off < 256; off <<= 1) {
        int val = 0;
        if (t >= off) val = part[t - off];
        __syncthreads();
        if (t >= off) part[t] += val;
        __syncthreads();
    }

    int run = (t == 0) ? 0 : part[t - 1];
    for (int i = 0; i < SCAN_PER_T; ++i) {
        const int idx = base + i;
        if (idx < NNODES) {
            rowptr[idx] = run;
            run += deg[idx];
        } else if (idx == NNODES) {
            rowptr[NNODES] = run;
        }
    }
}

// ---------------- CSR build: fill buckets ----------------
__global__ __launch_bounds__(256) void fill_kernel(
    const int* __restrict__ dstI, int* __restrict__ deg,
    const int* __restrict__ rowptr, int* __restrict__ ebuf)
{
    const int e = blockIdx.x * 256 + threadIdx.x;
    if (e >= NEDGES) return;
    const int d = dstI[e];
    const int p = atomicSub(&deg[d], 1) - 1;
    ebuf[rowptr[d] + p] = e;
}

// ---------------- per-(edge,head) attention logits ----------------
__global__ __launch_bounds__(256) void score_kernel(
    const float* __restrict__ q, const float* __restrict__ k,
    const int* __restrict__ srcI, const int* __restrict__ dstI,
    float* __restrict__ sc)
{
    const int idx = blockIdx.x * 256 + threadIdx.x;
    if (idx >= NEDGES * NH) return;
    const int e = idx >> 3;
    const int h = idx & 7;
    const int s = srcI[e];
    const int d = dstI[e];

    const float4* qp = (const float4*)(q + (size_t)d * ND + h * CH);
    const float4* kp = (const float4*)(k + (size_t)s * ND + h * CH);
    float acc = 0.0f;
    #pragma unroll
    for (int i = 0; i < CH / 4; ++i) {
        const float4 a = qp[i];
        const float4 b = kp[i];
        acc += a.x * b.x + a.y * b.y + a.z * b.z + a.w * b.w;
    }
    sc[idx] = acc * 0.17677669529663687f;   // 1/sqrt(32)
}

// ---------------- per-node gather: softmax + weighted V ----------------
__global__ __launch_bounds__(256) void gather_kernel(
    const float* __restrict__ v, const float* __restrict__ sc,
    const int* __restrict__ srcI,
    const int* __restrict__ rowptr, const int* __restrict__ ebuf,
    float* __restrict__ outp)
{
    const int d   = blockIdx.x;
    const int t   = threadIdx.x;
    const int h   = t >> 5;
    const int beg = rowptr[d];
    const int end = rowptr[d + 1];
    if (beg == end) return;

    float m = -3.0e38f;
    for (int j = beg; j < end; ++j) {
        const int e = ebuf[j];
        m = fmaxf(m, sc[(size_t)e * NH + h]);
    }

    float den = 0.0f, acc = 0.0f;
    for (int j = beg; j < end; ++j) {
        const int e = ebuf[j];
        const int s = srcI[e];
        const float p = __expf(sc[(size_t)e * NH + h] - m);
        den += p;
        acc += p * v[(size_t)s * ND + t];
    }

    outp[(size_t)d * ND + t] += acc / den;
}

extern "C" void kernel_launch(void* const* d_in, const int* in_sizes, int n_in,
                              void* d_out, int out_size, void* d_ws, size_t ws_size,
                              hipStream_t stream)
{
    const float* x   = (const float*)d_in[0];
    const int*   ei  = (const int*)d_in[1];   // [2, E] int32 per harness contract
    const float* Wq  = (const float*)d_in[2];
    const float* bq  = (const float*)d_in[3];
    const float* Wk  = (const float*)d_in[4];
    const float* bk  = (const float*)d_in[5];
    const float* Wv  = (const float*)d_in[6];
    const float* bv  = (const float*)d_in[7];
    const float* Wsk = (const float*)d_in[8];
    const float* bsk = (const float*)d_in[9];
    float* outp = (float*)d_out;

    // workspace: q,k,v,sc f32; xb,wt bf16; CSR ints  (~48 MB)
    float* q   = (float*)d_ws;
    float* k   = q + (size_t)NNODES * ND;
    float* v   = k + (size_t)NNODES * ND;
    float* sc  = v + (size_t)NNODES * ND;
    u16* xb    = (u16*)(sc + (size_t)NEDGES * NH);
    u16* wt    = xb + (size_t)NNODES * KDIM;
    int* deg    = (int*)(wt + 4 * 65536);
    int* rowptr = deg + NNODES;
    int* ebuf   = rowptr + (NNODES + 1);

    const int* srcI = ei;            // edge_index[0] = source j
    const int* dstI = ei + NEDGES;   // edge_index[1] = target i

    (void)hipMemsetAsync(deg, 0, NNODES * sizeof(int), stream);

    convx_kernel<<<(NNODES * KDIM / 8 + 255) / 256, 256, 0, stream>>>(x, xb);
    convw_kernel<<<(4 * 65536) / 256, 256, 0, stream>>>(Wq, Wk, Wv, Wsk, wt);

    const int eb = (NEDGES + 255) / 256;
    hist_kernel<<<eb, 256, 0, stream>>>(dstI, deg);
    scan_kernel<<<1, 256, 0, stream>>>(deg, rowptr);
    fill_kernel<<<eb, 256, 0, stream>>>(dstI, deg, rowptr, ebuf);

    dim3 gGemm((NNODES + GBM - 1) / GBM, ND / GBM, 4);
    mfma_gemm_kernel<<<gGemm, 256, 0, stream>>>(xb, wt, bq, bk, bv, bsk,
                                                q, k, v, outp);

    const int sb = (NEDGES * NH + 255) / 256;
    score_kernel<<<sb, 256, 0, stream>>>(q, k, srcI, dstI, sc);

    gather_kernel<<<NNODES, 256, 0, stream>>>(v, sc, srcI, rowptr, ebuf, outp);
}

// Round 16
// 279.123 us; speedup vs baseline: 16.1719x; 1.5019x over previous
//
#include <hip/hip_runtime.h>

#define NNODES 10000
#define NEDGES 320000
#define KDIM   256     // NIN
#define NH     8       // heads
#define CH     32      // channels/head
#define ND     256     // NH*CH

typedef unsigned short u16;
typedef __attribute__((ext_vector_type(8))) short bf16x8;   // 8 bf16 (4 VGPRs)
typedef __attribute__((ext_vector_type(8))) u16  u16x8;
typedef __attribute__((ext_vector_type(4))) float f32x4;

__device__ inline u16 f2bf(float f) {   // round-to-nearest-even f32 -> bf16
    unsigned int u = __float_as_uint(f);
    return (u16)((u + 0x7FFFu + ((u >> 16) & 1u)) >> 16);
}
__device__ inline float bf2f(u16 b) {
    return __uint_as_float(((unsigned int)b) << 16);
}

// ---------------- fused prep: convx | convw | hist (branch on block range) ----
#define CVX_BLK 1250   // NNODES*KDIM/8/256
#define CVW_BLK 1024   // 4*65536/256
#define HST_BLK 1250   // NEDGES/256

__global__ __launch_bounds__(256) void prep_kernel(
    const float* __restrict__ x, u16* __restrict__ xb,
    const float* __restrict__ Wq, const float* __restrict__ Wk,
    const float* __restrict__ Wv, const float* __restrict__ Wsk,
    u16* __restrict__ wt,
    const int* __restrict__ dstI, int* __restrict__ deg)
{
    const int b = blockIdx.x;
    if (b < CVX_BLK) {
        const size_t i8 = ((size_t)b * 256 + threadIdx.x) * 8;
        const float4 a = *(const float4*)(x + i8);
        const float4 c = *(const float4*)(x + i8 + 4);
        u16x8 o;
        o[0] = f2bf(a.x); o[1] = f2bf(a.y); o[2] = f2bf(a.z); o[3] = f2bf(a.w);
        o[4] = f2bf(c.x); o[5] = f2bf(c.y); o[6] = f2bf(c.z); o[7] = f2bf(c.w);
        *(u16x8*)(xb + i8) = o;
    } else if (b < CVX_BLK + CVW_BLK) {
        const int tid = (b - CVX_BLK) * 256 + threadIdx.x;   // 0..262143
        const int mat = tid >> 16;
        const int rem = tid & 65535;
        const int n   = rem >> 8;
        const int kk  = rem & 255;
        const float* W = (mat == 0) ? Wq : (mat == 1) ? Wk : (mat == 2) ? Wv : Wsk;
        wt[tid] = f2bf(W[kk * 256 + n]);   // wt[mat][n][kk] = W[kk][n]
    } else {
        const int e = (b - CVX_BLK - CVW_BLK) * 256 + threadIdx.x;
        if (e < NEDGES) atomicAdd(&deg[dstI[e]], 1);
    }
}

// ---------------- CSR build: exclusive prefix scan (single block) ----------------
#define SCAN_PER_T 40   // 256 * 40 = 10240 >= NNODES
__global__ __launch_bounds__(256) void scan_kernel(
    const int* __restrict__ deg, int* __restrict__ rowptr)
{
    __shared__ int part[256];
    const int t = threadIdx.x;
    const int base = t * SCAN_PER_T;

    int s = 0;
    for (int i = 0; i < SCAN_PER_T; ++i) {
        const int idx = base + i;
        if (idx < NNODES) s += deg[idx];
    }
    part[t] = s;
    __syncthreads();

    for (int off = 1; off < 256; off <<= 1) {
        int val = 0;
        if (t >= off) val = part[t - off];
        __syncthreads();
        if (t >= off) part[t] += val;
        __syncthreads();
    }

    int run = (t == 0) ? 0 : part[t - 1];
    for (int i = 0; i < SCAN_PER_T; ++i) {
        const int idx = base + i;
        if (idx < NNODES) {
            rowptr[idx] = run;
            run += deg[idx];
        } else if (idx == NNODES) {
            rowptr[NNODES] = run;
        }
    }
}

// ---------------- CSR build: fill buckets with SOURCE node ids ----------------
__global__ __launch_bounds__(256) void fill_kernel(
    const int* __restrict__ srcI, const int* __restrict__ dstI,
    int* __restrict__ deg, const int* __restrict__ rowptr,
    int* __restrict__ sbuf)
{
    const int e = blockIdx.x * 256 + threadIdx.x;
    if (e >= NEDGES) return;
    const int d = dstI[e];
    const int p = atomicSub(&deg[d], 1) - 1;
    sbuf[rowptr[d] + p] = srcI[e];   // store src directly (edge id not needed later)
}

// ---------------- MFMA GEMM: q,skip f32; k,v bf16 outputs ----------------
#define GBM 128
#define GBK 32
#define LDA 40   // padded LDS row stride (bf16 units)

__global__ __launch_bounds__(256) void mfma_gemm_kernel(
    const u16* __restrict__ xb, const u16* __restrict__ wt,
    const float* __restrict__ bq, const float* __restrict__ bk,
    const float* __restrict__ bv, const float* __restrict__ bsk,
    float* __restrict__ q, u16* __restrict__ kb, u16* __restrict__ vb,
    float* __restrict__ outp)
{
    __shared__ u16 As[GBM * LDA];
    __shared__ u16 Bs[GBM * LDA];

    const int mat = blockIdx.z;
    const float* bias = (mat == 0) ? bq : (mat == 1) ? bk : (mat == 2) ? bv : bsk;

    const int tid  = threadIdx.x;
    const int lane = tid & 63;
    const int wid  = tid >> 6;
    const int wr   = wid >> 1;
    const int wc   = wid & 1;
    const int row0 = blockIdx.x * GBM;
    const int col0 = blockIdx.y * GBM;

    const int fr = lane & 15;
    const int kg = (lane >> 4) * 8;

    f32x4 acc[4][4] = {};

    const u16* wbase = wt + (size_t)mat * 65536;

    for (int kt = 0; kt < KDIM; kt += GBK) {
        #pragma unroll
        for (int it = 0; it < 2; ++it) {
            const int c   = tid + it * 256;
            const int row = c >> 2;
            const int k8  = (c & 3) * 8;
            const int ga  = min(row0 + row, NNODES - 1);
            *(bf16x8*)&As[row * LDA + k8] =
                *(const bf16x8*)(xb + (size_t)ga * KDIM + kt + k8);
            *(bf16x8*)&Bs[row * LDA + k8] =
                *(const bf16x8*)(wbase + (size_t)(col0 + row) * KDIM + kt + k8);
        }
        __syncthreads();

        bf16x8 a[4], b[4];
        #pragma unroll
        for (int i = 0; i < 4; ++i)
            a[i] = *(bf16x8*)&As[(wr * 64 + i * 16 + fr) * LDA + kg];
        #pragma unroll
        for (int j = 0; j < 4; ++j)
            b[j] = *(bf16x8*)&Bs[(wc * 64 + j * 16 + fr) * LDA + kg];

        #pragma unroll
        for (int i = 0; i < 4; ++i)
            #pragma unroll
            for (int j = 0; j < 4; ++j)
                acc[i][j] = __builtin_amdgcn_mfma_f32_16x16x32_bf16(
                    a[i], b[j], acc[i][j], 0, 0, 0);
        __syncthreads();
    }

    // epilogue: C/D layout col=lane&15, row=(lane>>4)*4+reg  [m89-verified]
    #pragma unroll
    for (int j = 0; j < 4; ++j) {
        const int ccol = col0 + wc * 64 + j * 16 + (lane & 15);
        const float bb = bias[ccol];
        #pragma unroll
        for (int i = 0; i < 4; ++i) {
            const int rbase = row0 + wr * 64 + i * 16 + (lane >> 4) * 4;
            #pragma unroll
            for (int r = 0; r < 4; ++r) {
                const int row = rbase + r;
                if (row < NNODES) {
                    const float val = acc[i][j][r] + bb;
                    const size_t off = (size_t)row * ND + ccol;
                    if (mat == 0)      q[off]    = val;
                    else if (mat == 1) kb[off]   = f2bf(val);
                    else if (mat == 2) vb[off]   = f2bf(val);
                    else               outp[off] = val;
                }
            }
        }
    }
}

// ---------------- fused per-node attention: score + online softmax + PV ------
// One block per dst node d; thread t = (h = t>>5, c = t&31) owns out[d][t].
__global__ __launch_bounds__(256) void attn_kernel(
    const float* __restrict__ q, const u16* __restrict__ kb,
    const u16* __restrict__ vb,
    const int* __restrict__ rowptr, const int* __restrict__ sbuf,
    float* __restrict__ outp)
{
    const int d   = blockIdx.x;
    const int t   = threadIdx.x;
    const int beg = rowptr[d];
    const int end = rowptr[d + 1];
    if (beg == end) return;   // no incoming edges: out = skip only

    const float qc = q[(size_t)d * ND + t] * 0.17677669529663687f;  // 1/sqrt(32)

    float m = -3.0e38f, den = 0.0f, acc = 0.0f;
    for (int j = beg; j < end; ++j) {
        const int s = sbuf[j];
        const float kx = bf2f(kb[(size_t)s * ND + t]);
        const float vx = bf2f(vb[(size_t)s * ND + t]);

        float dot = qc * kx;
        #pragma unroll
        for (int off = 1; off < 32; off <<= 1)
            dot += __shfl_xor(dot, off, 32);   // per-head (32-lane) reduction

        const float mn    = fmaxf(m, dot);
        const float scale = __expf(m - mn);    // first iter: exp(-huge)=0
        const float p     = __expf(dot - mn);
        den = den * scale + p;
        acc = acc * scale + p * vx;
        m   = mn;
    }

    outp[(size_t)d * ND + t] += acc / den;
}

extern "C" void kernel_launch(void* const* d_in, const int* in_sizes, int n_in,
                              void* d_out, int out_size, void* d_ws, size_t ws_size,
                              hipStream_t stream)
{
    const float* x   = (const float*)d_in[0];
    const int*   ei  = (const int*)d_in[1];   // [2, E] int32 per harness contract
    const float* Wq  = (const float*)d_in[2];
    const float* bq  = (const float*)d_in[3];
    const float* Wk  = (const float*)d_in[4];
    const float* bk  = (const float*)d_in[5];
    const float* Wv  = (const float*)d_in[6];
    const float* bv  = (const float*)d_in[7];
    const float* Wsk = (const float*)d_in[8];
    const float* bsk = (const float*)d_in[9];
    float* outp = (float*)d_out;

    // workspace: q f32; kb,vb bf16; xb,wt bf16; CSR ints  (~33 MB)
    float* q   = (float*)d_ws;                    // 10.24 MB
    u16* kb    = (u16*)(q + (size_t)NNODES * ND); // 5.12 MB
    u16* vb    = kb + (size_t)NNODES * ND;        // 5.12 MB
    u16* xb    = vb + (size_t)NNODES * ND;        // 5.12 MB
    u16* wt    = xb + (size_t)NNODES * KDIM;      // 0.52 MB
    int* deg    = (int*)(wt + 4 * 65536);
    int* rowptr = deg + NNODES;
    int* sbuf   = rowptr + (NNODES + 1);

    const int* srcI = ei;            // edge_index[0] = source j
    const int* dstI = ei + NEDGES;   // edge_index[1] = target i

    (void)hipMemsetAsync(deg, 0, NNODES * sizeof(int), stream);

    prep_kernel<<<CVX_BLK + CVW_BLK + HST_BLK, 256, 0, stream>>>(
        x, xb, Wq, Wk, Wv, Wsk, wt, dstI, deg);

    scan_kernel<<<1, 256, 0, stream>>>(deg, rowptr);

    fill_kernel<<<(NEDGES + 255) / 256, 256, 0, stream>>>(
        srcI, dstI, deg, rowptr, sbuf);

    dim3 gGemm((NNODES + GBM - 1) / GBM, ND / GBM, 4);
    mfma_gemm_kernel<<<gGemm, 256, 0, stream>>>(xb, wt, bq, bk, bv, bsk,
                                                q, kb, vb, outp);

    attn_kernel<<<NNODES, 256, 0, stream>>>(q, kb, vb, rowptr, sbuf, outp);
}

// Round 19
// 222.966 us; speedup vs baseline: 20.2450x; 1.2519x over previous
//
#include <hip/hip_runtime.h>

#define NNODES 10000
#define NEDGES 320000
#define KDIM   256     // NIN
#define NH     8       // heads
#define CH     32      // channels/head
#define ND     256     // NH*CH

typedef unsigned short u16;
typedef __attribute__((ext_vector_type(8))) short bf16x8;   // 8 bf16 (4 VGPRs)
typedef __attribute__((ext_vector_type(8))) u16  u16x8;
typedef __attribute__((ext_vector_type(4))) u16  u16x4;
typedef __attribute__((ext_vector_type(4))) float f32x4;

__device__ inline u16 f2bf(float f) {   // round-to-nearest-even f32 -> bf16
    unsigned int u = __float_as_uint(f);
    return (u16)((u + 0x7FFFu + ((u >> 16) & 1u)) >> 16);
}
__device__ inline float bf2f(u16 b) {
    return __uint_as_float(((unsigned int)b) << 16);
}

// ---------------- fused prep: convx | convw | hist (branch on block range) ----
#define CVX_BLK 1250   // NNODES*KDIM/8/256
#define CVW_BLK 1024   // 4*65536/256
#define HST_BLK 1250   // NEDGES/256

__global__ __launch_bounds__(256) void prep_kernel(
    const float* __restrict__ x, u16* __restrict__ xb,
    const float* __restrict__ Wq, const float* __restrict__ Wk,
    const float* __restrict__ Wv, const float* __restrict__ Wsk,
    u16* __restrict__ wt,
    const int* __restrict__ dstI, int* __restrict__ deg)
{
    const int b = blockIdx.x;
    if (b < CVX_BLK) {
        const size_t i8 = ((size_t)b * 256 + threadIdx.x) * 8;
        const float4 a = *(const float4*)(x + i8);
        const float4 c = *(const float4*)(x + i8 + 4);
        u16x8 o;
        o[0] = f2bf(a.x); o[1] = f2bf(a.y); o[2] = f2bf(a.z); o[3] = f2bf(a.w);
        o[4] = f2bf(c.x); o[5] = f2bf(c.y); o[6] = f2bf(c.z); o[7] = f2bf(c.w);
        *(u16x8*)(xb + i8) = o;
    } else if (b < CVX_BLK + CVW_BLK) {
        const int tid = (b - CVX_BLK) * 256 + threadIdx.x;   // 0..262143
        const int mat = tid >> 16;
        const int rem = tid & 65535;
        const int n   = rem >> 8;
        const int kk  = rem & 255;
        const float* W = (mat == 0) ? Wq : (mat == 1) ? Wk : (mat == 2) ? Wv : Wsk;
        wt[tid] = f2bf(W[kk * 256 + n]);   // wt[mat][n][kk] = W[kk][n]
    } else {
        const int e = (b - CVX_BLK - CVW_BLK) * 256 + threadIdx.x;
        if (e < NEDGES) atomicAdd(&deg[dstI[e]], 1);
    }
}

// ---------------- CSR build: exclusive prefix scan (single block) ----------------
#define SCAN_PER_T 40   // 256 * 40 = 10240 >= NNODES
__global__ __launch_bounds__(256) void scan_kernel(
    const int* __restrict__ deg, int* __restrict__ rowptr)
{
    __shared__ int part[256];
    const int t = threadIdx.x;
    const int base = t * SCAN_PER_T;

    int s = 0;
    for (int i = 0; i < SCAN_PER_T; ++i) {
        const int idx = base + i;
        if (idx < NNODES) s += deg[idx];
    }
    part[t] = s;
    __syncthreads();

    for (int off = 1; off < 256; off <<= 1) {
        int val = 0;
        if (t >= off) val = part[t - off];
        __syncthreads();
        if (t >= off) part[t] += val;
        __syncthreads();
    }

    int run = (t == 0) ? 0 : part[t - 1];
    for (int i = 0; i < SCAN_PER_T; ++i) {
        const int idx = base + i;
        if (idx < NNODES) {
            rowptr[idx] = run;
            run += deg[idx];
        } else if (idx == NNODES) {
            rowptr[NNODES] = run;
        }
    }
}

// ---------------- CSR build: fill buckets with SOURCE node ids ----------------
__global__ __launch_bounds__(256) void fill_kernel(
    const int* __restrict__ srcI, const int* __restrict__ dstI,
    int* __restrict__ deg, const int* __restrict__ rowptr,
    int* __restrict__ sbuf)
{
    const int e = blockIdx.x * 256 + threadIdx.x;
    if (e >= NEDGES) return;
    const int d = dstI[e];
    const int p = atomicSub(&deg[d], 1) - 1;
    sbuf[rowptr[d] + p] = srcI[e];   // store src directly
}

// ---------------- MFMA GEMM: q,skip f32; k,v bf16 outputs ----------------
#define GBM 128
#define GBK 32
#define LDA 40   // padded LDS row stride (bf16 units)

__global__ __launch_bounds__(256) void mfma_gemm_kernel(
    const u16* __restrict__ xb, const u16* __restrict__ wt,
    const float* __restrict__ bq, const float* __restrict__ bk,
    const float* __restrict__ bv, const float* __restrict__ bsk,
    float* __restrict__ q, u16* __restrict__ kb, u16* __restrict__ vb,
    float* __restrict__ outp)
{
    __shared__ u16 As[GBM * LDA];
    __shared__ u16 Bs[GBM * LDA];

    const int mat = blockIdx.z;
    const float* bias = (mat == 0) ? bq : (mat == 1) ? bk : (mat == 2) ? bv : bsk;

    const int tid  = threadIdx.x;
    const int lane = tid & 63;
    const int wid  = tid >> 6;
    const int wr   = wid >> 1;
    const int wc   = wid & 1;
    const int row0 = blockIdx.x * GBM;
    const int col0 = blockIdx.y * GBM;

    const int fr = lane & 15;
    const int kg = (lane >> 4) * 8;

    f32x4 acc[4][4] = {};

    const u16* wbase = wt + (size_t)mat * 65536;

    for (int kt = 0; kt < KDIM; kt += GBK) {
        #pragma unroll
        for (int it = 0; it < 2; ++it) {
            const int c   = tid + it * 256;
            const int row = c >> 2;
            const int k8  = (c & 3) * 8;
            const int ga  = min(row0 + row, NNODES - 1);
            *(bf16x8*)&As[row * LDA + k8] =
                *(const bf16x8*)(xb + (size_t)ga * KDIM + kt + k8);
            *(bf16x8*)&Bs[row * LDA + k8] =
                *(const bf16x8*)(wbase + (size_t)(col0 + row) * KDIM + kt + k8);
        }
        __syncthreads();

        bf16x8 a[4], b[4];
        #pragma unroll
        for (int i = 0; i < 4; ++i)
            a[i] = *(bf16x8*)&As[(wr * 64 + i * 16 + fr) * LDA + kg];
        #pragma unroll
        for (int j = 0; j < 4; ++j)
            b[j] = *(bf16x8*)&Bs[(wc * 64 + j * 16 + fr) * LDA + kg];

        #pragma unroll
        for (int i = 0; i < 4; ++i)
            #pragma unroll
            for (int j = 0; j < 4; ++j)
                acc[i][j] = __builtin_amdgcn_mfma_f32_16x16x32_bf16(
                    a[i], b[j], acc[i][j], 0, 0, 0);
        __syncthreads();
    }

    // epilogue: C/D layout col=lane&15, row=(lane>>4)*4+reg  [m89-verified]
    #pragma unroll
    for (int j = 0; j < 4; ++j) {
        const int ccol = col0 + wc * 64 + j * 16 + (lane & 15);
        const float bb = bias[ccol];
        #pragma unroll
        for (int i = 0; i < 4; ++i) {
            const int rbase = row0 + wr * 64 + i * 16 + (lane >> 4) * 4;
            #pragma unroll
            for (int r = 0; r < 4; ++r) {
                const int row = rbase + r;
                if (row < NNODES) {
                    const float val = acc[i][j][r] + bb;
                    const size_t off = (size_t)row * ND + ccol;
                    if (mat == 0)      q[off]    = val;
                    else if (mat == 1) kb[off]   = f2bf(val);
                    else if (mat == 2) vb[off]   = f2bf(val);
                    else               outp[off] = val;
                }
            }
        }
    }
}

// ---------------- fused per-node attention v2: 4-wave edge-parallel ----------
// Block = 4 waves; lane l owns channels 4l..4l+3 (head = l>>3, 8 lanes/head).
// Wave w processes edges beg+w, beg+w+4, ... with private online softmax
// (m, den, acc[4]); LDS merge combines the 4 partials exactly.
__global__ __launch_bounds__(256) void attn_kernel(
    const float* __restrict__ q, const u16* __restrict__ kb,
    const u16* __restrict__ vb,
    const int* __restrict__ rowptr, const int* __restrict__ sbuf,
    float* __restrict__ outp)
{
    __shared__ float lds_m[4][8];
    __shared__ float lds_den[4][8];
    __shared__ float lds_acc[4][256];

    const int d   = blockIdx.x;
    const int beg = rowptr[d];
    const int end = rowptr[d + 1];
    if (beg == end) return;   // no incoming edges: out = skip only

    const int tid = threadIdx.x;
    const int w   = tid >> 6;     // wave 0..3
    const int l   = tid & 63;     // lane; channels 4l..4l+3

    float4 qc = *(const float4*)(q + (size_t)d * ND + 4 * l);
    qc.x *= 0.17677669529663687f;   // 1/sqrt(32)
    qc.y *= 0.17677669529663687f;
    qc.z *= 0.17677669529663687f;
    qc.w *= 0.17677669529663687f;

    float m = -3.0e38f, den = 0.0f;
    float a0 = 0.0f, a1 = 0.0f, a2 = 0.0f, a3 = 0.0f;

    for (int j = beg + w; j < end; j += 4) {
        const int s = sbuf[j];
        const u16x4 k4 = *(const u16x4*)(kb + (size_t)s * ND + 4 * l);
        const u16x4 v4 = *(const u16x4*)(vb + (size_t)s * ND + 4 * l);

        float dot = qc.x * bf2f(k4[0]) + qc.y * bf2f(k4[1])
                  + qc.z * bf2f(k4[2]) + qc.w * bf2f(k4[3]);
        dot += __shfl_xor(dot, 1, 8);   // reduce across the head's 8 lanes
        dot += __shfl_xor(dot, 2, 8);
        dot += __shfl_xor(dot, 4, 8);

        const float mn = fmaxf(m, dot);
        const float sc = __expf(m - mn);    // first iter: exp(-huge)=0
        const float p  = __expf(dot - mn);
        den = den * sc + p;
        a0  = a0 * sc + p * bf2f(v4[0]);
        a1  = a1 * sc + p * bf2f(v4[1]);
        a2  = a2 * sc + p * bf2f(v4[2]);
        a3  = a3 * sc + p * bf2f(v4[3]);
        m   = mn;
    }

    if ((l & 7) == 0) {               // one writer per head per wave
        lds_m[w][l >> 3]   = m;
        lds_den[w][l >> 3] = den;
    }
    lds_acc[w][4 * l + 0] = a0;
    lds_acc[w][4 * l + 1] = a1;
    lds_acc[w][4 * l + 2] = a2;
    lds_acc[w][4 * l + 3] = a3;
    __syncthreads();

    // merge: thread t owns channel t (head h = t>>5)
    const int h = tid >> 5;
    const float M = fmaxf(fmaxf(lds_m[0][h], lds_m[1][h]),
                          fmaxf(lds_m[2][h], lds_m[3][h]));
    float D = 0.0f, A = 0.0f;
    #pragma unroll
    for (int ww = 0; ww < 4; ++ww) {
        const float s_ = __expf(lds_m[ww][h] - M);   // empty wave: exp(-huge)=0
        D += lds_den[ww][h] * s_;
        A += lds_acc[ww][tid] * s_;
    }

    outp[(size_t)d * ND + tid] += A / D;
}

extern "C" void kernel_launch(void* const* d_in, const int* in_sizes, int n_in,
                              void* d_out, int out_size, void* d_ws, size_t ws_size,
                              hipStream_t stream)
{
    const float* x   = (const float*)d_in[0];
    const int*   ei  = (const int*)d_in[1];   // [2, E] int32 per harness contract
    const float* Wq  = (const float*)d_in[2];
    const float* bq  = (const float*)d_in[3];
    const float* Wk  = (const float*)d_in[4];
    const float* bk  = (const float*)d_in[5];
    const float* Wv  = (const float*)d_in[6];
    const float* bv  = (const float*)d_in[7];
    const float* Wsk = (const float*)d_in[8];
    const float* bsk = (const float*)d_in[9];
    float* outp = (float*)d_out;

    // workspace: q f32; kb,vb bf16; xb,wt bf16; CSR ints  (~33 MB)
    float* q   = (float*)d_ws;                    // 10.24 MB
    u16* kb    = (u16*)(q + (size_t)NNODES * ND); // 5.12 MB
    u16* vb    = kb + (size_t)NNODES * ND;        // 5.12 MB
    u16* xb    = vb + (size_t)NNODES * ND;        // 5.12 MB
    u16* wt    = xb + (size_t)NNODES * KDIM;      // 0.52 MB
    int* deg    = (int*)(wt + 4 * 65536);
    int* rowptr = deg + NNODES;
    int* sbuf   = rowptr + (NNODES + 1);

    const int* srcI = ei;            // edge_index[0] = source j
    const int* dstI = ei + NEDGES;   // edge_index[1] = target i

    (void)hipMemsetAsync(deg, 0, NNODES * sizeof(int), stream);

    prep_kernel<<<CVX_BLK + CVW_BLK + HST_BLK, 256, 0, stream>>>(
        x, xb, Wq, Wk, Wv, Wsk, wt, dstI, deg);

    scan_kernel<<<1, 256, 0, stream>>>(deg, rowptr);

    fill_kernel<<<(NEDGES + 255) / 256, 256, 0, stream>>>(
        srcI, dstI, deg, rowptr, sbuf);

    dim3 gGemm((NNODES + GBM - 1) / GBM, ND / GBM, 4);
    mfma_gemm_kernel<<<gGemm, 256, 0, stream>>>(xb, wt, bq, bk, bv, bsk,
                                                q, kb, vb, outp);

    attn_kernel<<<NNODES, 256, 0, stream>>>(q, kb, vb, rowptr, sbuf, outp);
}